// Round 1
// baseline (107.561 us; speedup 1.0000x reference)
//
#include <hip/hip_runtime.h>

#define NBATCH 256
#define NJ     62
#define NV     14522
#define NCORE  28
#define BPB    4      // batches per thread in skin kernel

// ---------------------------------------------------------------------------
// Kernel 1: per-batch forward kinematics. One block per batch, 64 threads.
// Computes R (euler zyx), bone factors, A = [R|off], tree-level-parallel FK,
// J_out, and the skinning transforms G' = [Rg | tg - Rg*Jt] -> Gout (B*K*12).
// ---------------------------------------------------------------------------
__global__ __launch_bounds__(64) void fk_kernel(
    const float* __restrict__ thetas,   // (B, K*3)
    const float* __restrict__ blc,      // (B, NCORE)
    const float* __restrict__ cbl,      // (B, 1)
    const float* __restrict__ trans,    // (B, 3)
    const float* __restrict__ scale,    // (B,)
    const float* __restrict__ tpose,    // (K, 3)
    const int*   __restrict__ parents,  // (K,)
    const int*   __restrict__ mapper,   // (K,)
    float* __restrict__ Gout,           // (B, K, 12) rows of [R' | t']
    float* __restrict__ Jout)           // (B, K, 3)
{
    __shared__ float Asm[NJ][12];
    __shared__ float Gsm[NJ][12];

    const int b = blockIdx.x;
    const int k = threadIdx.x;
    int p = 0;

    if (k < NJ) {
        p = parents[k];
        const float tz = thetas[(b * NJ + k) * 3 + 0];
        const float ty = thetas[(b * NJ + k) * 3 + 1];
        const float tx = thetas[(b * NJ + k) * 3 + 2];
        const float cx = cosf(tx), sx = sinf(tx);
        const float cy = cosf(ty), sy = sinf(ty);
        const float cz = cosf(tz), sz = sinf(tz);
        // R = Rz @ Ry @ Rx
        const float r00 = cz * cy;
        const float r01 = cz * sy * sx - sz * cx;
        const float r02 = sz * sx + cz * sy * cx;
        const float r10 = sz * cy;
        const float r11 = cz * cx + sz * sy * sx;
        const float r12 = sz * sy * cx - cz * sx;
        const float r20 = -sy;
        const float r21 = cy * sx;
        const float r22 = cy * cx;

        // bone-length factor
        float f;
        const int m = mapper[k];
        if (k == 0)        f = 1.0f;
        else if (k == 1)   f = cbl[b];
        else if (m < 0)    f = 1.0f;
        else               f = 2.0f / (1.0f + expf(-blc[b * NCORE + m] * 0.2f));

        float ox, oy, oz;
        if (k == 0) {
            ox = tpose[0]; oy = tpose[1]; oz = tpose[2];
        } else {
            ox = (tpose[k * 3 + 0] - tpose[p * 3 + 0]) * f;
            oy = (tpose[k * 3 + 1] - tpose[p * 3 + 1]) * f;
            oz = (tpose[k * 3 + 2] - tpose[p * 3 + 2]) * f;
        }
        Asm[k][0] = r00; Asm[k][1] = r01; Asm[k][2]  = r02; Asm[k][3]  = ox;
        Asm[k][4] = r10; Asm[k][5] = r11; Asm[k][6]  = r12; Asm[k][7]  = oy;
        Asm[k][8] = r20; Asm[k][9] = r21; Asm[k][10] = r22; Asm[k][11] = oz;
    }
    __syncthreads();

    if (k == 0) {
        #pragma unroll
        for (int j = 0; j < 12; ++j) Gsm[0][j] = Asm[0][j];
    }
    __syncthreads();

    // depth(k) = floor(log2(k+1)); binary-tree levels 1..5
    const int depth = (k < NJ) ? (31 - __clz((unsigned)(k + 1))) : 99;
    for (int d = 1; d <= 5; ++d) {
        if (depth == d) {
            float gp[12], a[12], g[12];
            #pragma unroll
            for (int j = 0; j < 12; ++j) { gp[j] = Gsm[p][j]; a[j] = Asm[k][j]; }
            #pragma unroll
            for (int i = 0; i < 3; ++i) {
                #pragma unroll
                for (int j = 0; j < 4; ++j) {
                    float s = (j == 3) ? gp[i * 4 + 3] : 0.0f;
                    s = fmaf(gp[i * 4 + 0], a[0 * 4 + j], s);
                    s = fmaf(gp[i * 4 + 1], a[1 * 4 + j], s);
                    s = fmaf(gp[i * 4 + 2], a[2 * 4 + j], s);
                    g[i * 4 + j] = s;
                }
            }
            #pragma unroll
            for (int j = 0; j < 12; ++j) Gsm[k][j] = g[j];
        }
        __syncthreads();
    }

    if (k < NJ) {
        float g[12];
        #pragma unroll
        for (int j = 0; j < 12; ++j) g[j] = Gsm[k][j];
        const float jx = tpose[k * 3 + 0];
        const float jy = tpose[k * 3 + 1];
        const float jz = tpose[k * 3 + 2];
        const float s  = scale[b];
        const float t0 = trans[b * 3 + 0], t1 = trans[b * 3 + 1], t2 = trans[b * 3 + 2];
        // J_out = G.t * scale + trans  (pre-adjustment translation)
        Jout[(b * NJ + k) * 3 + 0] = fmaf(g[3],  s, t0);
        Jout[(b * NJ + k) * 3 + 1] = fmaf(g[7],  s, t1);
        Jout[(b * NJ + k) * 3 + 2] = fmaf(g[11], s, t2);
        // t' = t - R * Jt
        const float npx = g[3]  - (g[0] * jx + g[1] * jy + g[2]  * jz);
        const float npy = g[7]  - (g[4] * jx + g[5] * jy + g[6]  * jz);
        const float npz = g[11] - (g[8] * jx + g[9] * jy + g[10] * jz);
        float* go = Gout + ((size_t)b * NJ + k) * 12;
        go[0] = g[0]; go[1] = g[1]; go[2]  = g[2];  go[3]  = npx;
        go[4] = g[4]; go[5] = g[5]; go[6]  = g[6];  go[7]  = npy;
        go[8] = g[8]; go[9] = g[9]; go[10] = g[10]; go[11] = npz;
    }
}

// ---------------------------------------------------------------------------
// Kernel 2: transpose weights (V,K) -> (K,V) so the skin kernel's per-k
// weight read is lane-contiguous.
// ---------------------------------------------------------------------------
__global__ __launch_bounds__(256) void transpose_w(
    const float* __restrict__ W, float* __restrict__ Wt)
{
    const int v = blockIdx.x * 256 + threadIdx.x;
    if (v >= NV) return;
    #pragma unroll
    for (int kk = 0; kk < NJ; ++kk) Wt[kk * NV + v] = W[v * NJ + kk];
}

// ---------------------------------------------------------------------------
// Kernel 3: linear blend skinning. Each thread: 1 vertex x BPB batches.
// G addresses are wave-uniform -> scalar loads; weight read coalesced.
// ---------------------------------------------------------------------------
template <bool TRANSPOSED>
__global__ __launch_bounds__(256) void skin_kernel(
    const float* __restrict__ G,       // (B, K, 12)
    const float* __restrict__ W,       // (K,V) if TRANSPOSED else (V,K)
    const float* __restrict__ vtempl,  // (V, 3)
    const float* __restrict__ scale,   // (B,)
    const float* __restrict__ trans,   // (B, 3)
    float* __restrict__ out)           // (B, V, 3)
{
    const int v  = blockIdx.x * 256 + threadIdx.x;
    const int b0 = blockIdx.y * BPB;
    const bool valid = v < NV;
    const int vc = valid ? v : (NV - 1);

    const float hx = vtempl[vc * 3 + 0];
    const float hy = vtempl[vc * 3 + 1];
    const float hz = vtempl[vc * 3 + 2];

    float acc[BPB][3];
    #pragma unroll
    for (int bb = 0; bb < BPB; ++bb) {
        acc[bb][0] = 0.0f; acc[bb][1] = 0.0f; acc[bb][2] = 0.0f;
    }

    #pragma unroll 2
    for (int kk = 0; kk < NJ; ++kk) {
        const float wk = TRANSPOSED ? W[kk * NV + vc] : W[(size_t)vc * NJ + kk];
        #pragma unroll
        for (int bb = 0; bb < BPB; ++bb) {
            const float* g = G + ((size_t)(b0 + bb) * NJ + kk) * 12;
            const float t0 = fmaf(g[0], hx, fmaf(g[1], hy, fmaf(g[2],  hz, g[3])));
            const float t1 = fmaf(g[4], hx, fmaf(g[5], hy, fmaf(g[6],  hz, g[7])));
            const float t2 = fmaf(g[8], hx, fmaf(g[9], hy, fmaf(g[10], hz, g[11])));
            acc[bb][0] = fmaf(wk, t0, acc[bb][0]);
            acc[bb][1] = fmaf(wk, t1, acc[bb][1]);
            acc[bb][2] = fmaf(wk, t2, acc[bb][2]);
        }
    }

    if (valid) {
        #pragma unroll
        for (int bb = 0; bb < BPB; ++bb) {
            const int b = b0 + bb;
            const float s  = scale[b];
            const float t0 = trans[b * 3 + 0];
            const float t1 = trans[b * 3 + 1];
            const float t2 = trans[b * 3 + 2];
            float* o = out + ((size_t)b * NV + v) * 3;
            o[0] = fmaf(acc[bb][0], s, t0);
            o[1] = fmaf(acc[bb][1], s, t1);
            o[2] = fmaf(acc[bb][2], s, t2);
        }
    }
}

extern "C" void kernel_launch(void* const* d_in, const int* in_sizes, int n_in,
                              void* d_out, int out_size, void* d_ws, size_t ws_size,
                              hipStream_t stream)
{
    const float* thetas  = (const float*)d_in[0];
    const float* blc     = (const float*)d_in[1];
    const float* cbl     = (const float*)d_in[2];
    const float* trans   = (const float*)d_in[3];
    const float* scale   = (const float*)d_in[4];
    const float* vtempl  = (const float*)d_in[5];
    const float* tpose   = (const float*)d_in[6];
    const float* weights = (const float*)d_in[7];
    const int*   parents = (const int*)d_in[8];
    const int*   mapper  = (const int*)d_in[9];

    float* out  = (float*)d_out;
    float* Jout = out + (size_t)NBATCH * NV * 3;

    float* Gws = (float*)d_ws;                       // B*K*12 floats
    const size_t g_elems = (size_t)NBATCH * NJ * 12;
    const size_t need_bytes = (g_elems + (size_t)NJ * NV) * sizeof(float);

    fk_kernel<<<NBATCH, 64, 0, stream>>>(thetas, blc, cbl, trans, scale, tpose,
                                         parents, mapper, Gws, Jout);

    const int vblocks = (NV + 255) / 256;
    if (ws_size >= need_bytes) {
        float* Wt = Gws + g_elems;
        transpose_w<<<vblocks, 256, 0, stream>>>(weights, Wt);
        skin_kernel<true><<<dim3(vblocks, NBATCH / BPB), 256, 0, stream>>>(
            Gws, Wt, vtempl, scale, trans, out);
    } else {
        skin_kernel<false><<<dim3(vblocks, NBATCH / BPB), 256, 0, stream>>>(
            Gws, weights, vtempl, scale, trans, out);
    }
}

// Round 2
// 70.193 us; speedup vs baseline: 1.5324x; 1.5324x over previous
//
#include <hip/hip_runtime.h>

#define NBATCH 256
#define NJ     62
#define NV     14522
#define NCORE  28
#define KPAD   256    // 62*4 = 248 padded to 256
#define NN     768    // 256 batches * 3 rows
#define MPAD   14528  // ceil(NV/64)*64

typedef __attribute__((ext_vector_type(8))) short short8v;   // 8 bf16
typedef __attribute__((ext_vector_type(4))) short short4v;   // 4 bf16
typedef __attribute__((ext_vector_type(4))) float floatx4;

static __device__ inline short f2bf(float x) {
    unsigned u = __float_as_uint(x);
    unsigned r = (u + 0x7fffu + ((u >> 16) & 1u)) >> 16;
    return (short)r;
}

// ---------------------------------------------------------------------------
// Kernel 1: per-batch forward kinematics. One block per batch, 64 threads.
// Writes J_out (fp32), and the skinning transforms in bf16 GEMM-B layout:
//   Bt[(b*3+i)*KPAD + k*4+j] = G'[b,k,i,j],  G' = [Rg | tg - Rg*Jt]
// Optionally writes fp32 G (fallback path).
// ---------------------------------------------------------------------------
__global__ __launch_bounds__(64) void fk_kernel(
    const float* __restrict__ thetas,   // (B, K*3)
    const float* __restrict__ blc,      // (B, NCORE)
    const float* __restrict__ cbl,      // (B, 1)
    const float* __restrict__ trans,    // (B, 3)
    const float* __restrict__ scale,    // (B,)
    const float* __restrict__ tpose,    // (K, 3)
    const int*   __restrict__ parents,  // (K,)
    const int*   __restrict__ mapper,   // (K,)
    short* __restrict__ Bt,             // (NN, KPAD) bf16, or null
    float* __restrict__ Gout,           // (B, K, 12) fp32, or null
    float* __restrict__ Jout)           // (B, K, 3)
{
    __shared__ float Asm[NJ][12];
    __shared__ float Gsm[NJ][12];

    const int b = blockIdx.x;
    const int k = threadIdx.x;
    int p = 0;

    if (k < NJ) {
        p = parents[k];
        const float tz = thetas[(b * NJ + k) * 3 + 0];
        const float ty = thetas[(b * NJ + k) * 3 + 1];
        const float tx = thetas[(b * NJ + k) * 3 + 2];
        const float cx = cosf(tx), sx = sinf(tx);
        const float cy = cosf(ty), sy = sinf(ty);
        const float cz = cosf(tz), sz = sinf(tz);
        // R = Rz @ Ry @ Rx
        const float r00 = cz * cy;
        const float r01 = cz * sy * sx - sz * cx;
        const float r02 = sz * sx + cz * sy * cx;
        const float r10 = sz * cy;
        const float r11 = cz * cx + sz * sy * sx;
        const float r12 = sz * sy * cx - cz * sx;
        const float r20 = -sy;
        const float r21 = cy * sx;
        const float r22 = cy * cx;

        float f;
        const int m = mapper[k];
        if (k == 0)        f = 1.0f;
        else if (k == 1)   f = cbl[b];
        else if (m < 0)    f = 1.0f;
        else               f = 2.0f / (1.0f + expf(-blc[b * NCORE + m] * 0.2f));

        float ox, oy, oz;
        if (k == 0) {
            ox = tpose[0]; oy = tpose[1]; oz = tpose[2];
        } else {
            ox = (tpose[k * 3 + 0] - tpose[p * 3 + 0]) * f;
            oy = (tpose[k * 3 + 1] - tpose[p * 3 + 1]) * f;
            oz = (tpose[k * 3 + 2] - tpose[p * 3 + 2]) * f;
        }
        Asm[k][0] = r00; Asm[k][1] = r01; Asm[k][2]  = r02; Asm[k][3]  = ox;
        Asm[k][4] = r10; Asm[k][5] = r11; Asm[k][6]  = r12; Asm[k][7]  = oy;
        Asm[k][8] = r20; Asm[k][9] = r21; Asm[k][10] = r22; Asm[k][11] = oz;
    }
    __syncthreads();

    if (k == 0) {
        #pragma unroll
        for (int j = 0; j < 12; ++j) Gsm[0][j] = Asm[0][j];
    }
    __syncthreads();

    const int depth = (k < NJ) ? (31 - __clz((unsigned)(k + 1))) : 99;
    for (int d = 1; d <= 5; ++d) {
        if (depth == d) {
            float gp[12], a[12], g[12];
            #pragma unroll
            for (int j = 0; j < 12; ++j) { gp[j] = Gsm[p][j]; a[j] = Asm[k][j]; }
            #pragma unroll
            for (int i = 0; i < 3; ++i) {
                #pragma unroll
                for (int j = 0; j < 4; ++j) {
                    float s = (j == 3) ? gp[i * 4 + 3] : 0.0f;
                    s = fmaf(gp[i * 4 + 0], a[0 * 4 + j], s);
                    s = fmaf(gp[i * 4 + 1], a[1 * 4 + j], s);
                    s = fmaf(gp[i * 4 + 2], a[2 * 4 + j], s);
                    g[i * 4 + j] = s;
                }
            }
            #pragma unroll
            for (int j = 0; j < 12; ++j) Gsm[k][j] = g[j];
        }
        __syncthreads();
    }

    if (k < NJ) {
        float g[12];
        #pragma unroll
        for (int j = 0; j < 12; ++j) g[j] = Gsm[k][j];
        const float jx = tpose[k * 3 + 0];
        const float jy = tpose[k * 3 + 1];
        const float jz = tpose[k * 3 + 2];
        const float s  = scale[b];
        const float t0 = trans[b * 3 + 0], t1 = trans[b * 3 + 1], t2 = trans[b * 3 + 2];
        Jout[(b * NJ + k) * 3 + 0] = fmaf(g[3],  s, t0);
        Jout[(b * NJ + k) * 3 + 1] = fmaf(g[7],  s, t1);
        Jout[(b * NJ + k) * 3 + 2] = fmaf(g[11], s, t2);
        // t' = t - R * Jt
        float np[3];
        np[0] = g[3]  - (g[0] * jx + g[1] * jy + g[2]  * jz);
        np[1] = g[7]  - (g[4] * jx + g[5] * jy + g[6]  * jz);
        np[2] = g[11] - (g[8] * jx + g[9] * jy + g[10] * jz);

        if (Gout) {
            float* go = Gout + ((size_t)b * NJ + k) * 12;
            go[0] = g[0]; go[1] = g[1]; go[2]  = g[2];  go[3]  = np[0];
            go[4] = g[4]; go[5] = g[5]; go[6]  = g[6];  go[7]  = np[1];
            go[8] = g[8]; go[9] = g[9]; go[10] = g[10]; go[11] = np[2];
        }
        if (Bt) {
            #pragma unroll
            for (int i = 0; i < 3; ++i) {
                short4v o;
                o[0] = f2bf(g[i * 4 + 0]);
                o[1] = f2bf(g[i * 4 + 1]);
                o[2] = f2bf(g[i * 4 + 2]);
                o[3] = f2bf(np[i]);
                *(short4v*)&Bt[(size_t)(b * 3 + i) * KPAD + k * 4] = o;
            }
            if (k == 0) {  // zero the K padding cols 248..255 for this batch's 3 rows
                short4v z = {0, 0, 0, 0};
                #pragma unroll
                for (int i = 0; i < 3; ++i) {
                    *(short4v*)&Bt[(size_t)(b * 3 + i) * KPAD + 248] = z;
                    *(short4v*)&Bt[(size_t)(b * 3 + i) * KPAD + 252] = z;
                }
            }
        }
    }
}

// ---------------------------------------------------------------------------
// Kernel 2: build WH (MPAD, KPAD) bf16:  WH[v][4k+j] = w[v,k] * h_v[j],
// h_v = (vt_x, vt_y, vt_z, 1). Rows >= NV and cols >= 248 are zero.
// Each thread writes one 16B chunk (2 joints).
// ---------------------------------------------------------------------------
__global__ __launch_bounds__(256) void build_wh(
    const float* __restrict__ W,      // (V, NJ)
    const float* __restrict__ vt,     // (V, 3)
    short* __restrict__ WH)
{
    const int id = blockIdx.x * 256 + threadIdx.x;   // MPAD*32 total
    const int v = id >> 5;
    const int c = id & 31;           // chunk: joints 2c, 2c+1
    const int k = c * 2;
    float w0 = 0.f, w1 = 0.f, hx = 0.f, hy = 0.f, hz = 0.f;
    if (v < NV) {
        hx = vt[v * 3 + 0]; hy = vt[v * 3 + 1]; hz = vt[v * 3 + 2];
        if (k < NJ)     w0 = W[(size_t)v * NJ + k];
        if (k + 1 < NJ) w1 = W[(size_t)v * NJ + k + 1];
    }
    short8v o;
    o[0] = f2bf(w0 * hx); o[1] = f2bf(w0 * hy); o[2] = f2bf(w0 * hz); o[3] = f2bf(w0);
    o[4] = f2bf(w1 * hx); o[5] = f2bf(w1 * hy); o[6] = f2bf(w1 * hz); o[7] = f2bf(w1);
    *(short8v*)&WH[(size_t)v * KPAD + c * 8] = o;
}

// ---------------------------------------------------------------------------
// Kernel 3: GEMM + epilogue.  OUT (MPAD x NN) = WH * Bt^T, then
// out[b,v,i] = OUT[v][3b+i]*scale[b] + trans[3b+i].
// Block = 4 waves (2x2), wave tile 32x32 (2x2 frags of 16x16x32 bf16 MFMA).
// ---------------------------------------------------------------------------
__global__ __launch_bounds__(256) void gemm_skin(
    const short* __restrict__ WH,     // (MPAD, KPAD) bf16
    const short* __restrict__ Bt,     // (NN, KPAD) bf16
    const float* __restrict__ scale,  // (B,)
    const float* __restrict__ trans,  // (B*3,) == per-n addend
    float* __restrict__ out)          // (B, V, 3)
{
    const int wave = threadIdx.x >> 6;        // 0..3
    const int lane = threadIdx.x & 63;
    const int wm = wave >> 1, wn = wave & 1;  // 2x2 wave grid
    const int m0 = blockIdx.x * 64 + wm * 32;
    const int n0 = blockIdx.y * 64 + wn * 32;
    const int lrow = lane & 15;
    const int lk8  = (lane >> 4) * 8;

    floatx4 acc[2][2];
    #pragma unroll
    for (int mt = 0; mt < 2; ++mt)
        #pragma unroll
        for (int nt = 0; nt < 2; ++nt)
            acc[mt][nt] = (floatx4){0.f, 0.f, 0.f, 0.f};

    #pragma unroll
    for (int k0 = 0; k0 < KPAD; k0 += 32) {
        short8v a[2], bfr[2];
        #pragma unroll
        for (int mt = 0; mt < 2; ++mt)
            a[mt] = *(const short8v*)&WH[(size_t)(m0 + mt * 16 + lrow) * KPAD + k0 + lk8];
        #pragma unroll
        for (int nt = 0; nt < 2; ++nt)
            bfr[nt] = *(const short8v*)&Bt[(size_t)(n0 + nt * 16 + lrow) * KPAD + k0 + lk8];
        #pragma unroll
        for (int mt = 0; mt < 2; ++mt)
            #pragma unroll
            for (int nt = 0; nt < 2; ++nt)
                acc[mt][nt] = __builtin_amdgcn_mfma_f32_16x16x32_bf16(
                    a[mt], bfr[nt], acc[mt][nt], 0, 0, 0);
    }

    // epilogue: D lane layout: row = (lane>>4)*4 + r, col = lane&15
    #pragma unroll
    for (int nt = 0; nt < 2; ++nt) {
        const int n = n0 + nt * 16 + lrow;
        const int bb = n / 3;
        const float s = scale[bb];
        const float t = trans[n];
        const size_t obase = (size_t)bb * NV;
        #pragma unroll
        for (int mt = 0; mt < 2; ++mt) {
            const int vbase = m0 + mt * 16 + (lane >> 4) * 4;
            #pragma unroll
            for (int r = 0; r < 4; ++r) {
                const int v = vbase + r;
                if (v < NV)
                    out[(obase + v) * 3 + (n - bb * 3)] = fmaf(acc[mt][nt][r], s, t);
            }
        }
    }
}

// ---------------------------------------------------------------------------
// Fallback (ws too small): fp32 vector skinning, direct weight reads.
// ---------------------------------------------------------------------------
#define BPB 4
__global__ __launch_bounds__(256) void skin_kernel(
    const float* __restrict__ G, const float* __restrict__ W,
    const float* __restrict__ vtempl, const float* __restrict__ scale,
    const float* __restrict__ trans, float* __restrict__ out)
{
    const int v  = blockIdx.x * 256 + threadIdx.x;
    const int b0 = blockIdx.y * BPB;
    const bool valid = v < NV;
    const int vc = valid ? v : (NV - 1);
    const float hx = vtempl[vc * 3 + 0];
    const float hy = vtempl[vc * 3 + 1];
    const float hz = vtempl[vc * 3 + 2];
    float acc[BPB][3];
    #pragma unroll
    for (int bb = 0; bb < BPB; ++bb) { acc[bb][0] = acc[bb][1] = acc[bb][2] = 0.f; }
    #pragma unroll 2
    for (int kk = 0; kk < NJ; ++kk) {
        const float wk = W[(size_t)vc * NJ + kk];
        #pragma unroll
        for (int bb = 0; bb < BPB; ++bb) {
            const float* g = G + ((size_t)(b0 + bb) * NJ + kk) * 12;
            const float t0 = fmaf(g[0], hx, fmaf(g[1], hy, fmaf(g[2],  hz, g[3])));
            const float t1 = fmaf(g[4], hx, fmaf(g[5], hy, fmaf(g[6],  hz, g[7])));
            const float t2 = fmaf(g[8], hx, fmaf(g[9], hy, fmaf(g[10], hz, g[11])));
            acc[bb][0] = fmaf(wk, t0, acc[bb][0]);
            acc[bb][1] = fmaf(wk, t1, acc[bb][1]);
            acc[bb][2] = fmaf(wk, t2, acc[bb][2]);
        }
    }
    if (valid) {
        #pragma unroll
        for (int bb = 0; bb < BPB; ++bb) {
            const int b = b0 + bb;
            const float s  = scale[b];
            float* o = out + ((size_t)b * NV + v) * 3;
            o[0] = fmaf(acc[bb][0], s, trans[b * 3 + 0]);
            o[1] = fmaf(acc[bb][1], s, trans[b * 3 + 1]);
            o[2] = fmaf(acc[bb][2], s, trans[b * 3 + 2]);
        }
    }
}

extern "C" void kernel_launch(void* const* d_in, const int* in_sizes, int n_in,
                              void* d_out, int out_size, void* d_ws, size_t ws_size,
                              hipStream_t stream)
{
    const float* thetas  = (const float*)d_in[0];
    const float* blc     = (const float*)d_in[1];
    const float* cbl     = (const float*)d_in[2];
    const float* trans   = (const float*)d_in[3];
    const float* scale   = (const float*)d_in[4];
    const float* vtempl  = (const float*)d_in[5];
    const float* tpose   = (const float*)d_in[6];
    const float* weights = (const float*)d_in[7];
    const int*   parents = (const int*)d_in[8];
    const int*   mapper  = (const int*)d_in[9];

    float* out  = (float*)d_out;
    float* Jout = out + (size_t)NBATCH * NV * 3;

    const size_t wh_bytes = (size_t)MPAD * KPAD * sizeof(short);   // 7.44 MB
    const size_t bt_bytes = (size_t)NN * KPAD * sizeof(short);     // 0.39 MB
    const size_t g_bytes  = (size_t)NBATCH * NJ * 12 * sizeof(float);

    if (ws_size >= wh_bytes + bt_bytes) {
        short* WH = (short*)d_ws;
        short* Bt = WH + (size_t)MPAD * KPAD;

        fk_kernel<<<NBATCH, 64, 0, stream>>>(thetas, blc, cbl, trans, scale, tpose,
                                             parents, mapper, Bt, nullptr, Jout);
        build_wh<<<(MPAD * 32) / 256, 256, 0, stream>>>(weights, vtempl, WH);
        gemm_skin<<<dim3(MPAD / 64, NN / 64), 256, 0, stream>>>(
            WH, Bt, scale, trans, out);
    } else {
        float* Gws = (float*)d_ws;
        fk_kernel<<<NBATCH, 64, 0, stream>>>(thetas, blc, cbl, trans, scale, tpose,
                                             parents, mapper, nullptr, Gws, Jout);
        const int vblocks = (NV + 255) / 256;
        skin_kernel<<<dim3(vblocks, NBATCH / BPB), 256, 0, stream>>>(
            Gws, weights, vtempl, scale, trans, out);
        (void)g_bytes;
    }
}

// Round 3
// 60.425 us; speedup vs baseline: 1.7801x; 1.1617x over previous
//
#include <hip/hip_runtime.h>

#define NBATCH 256
#define NJ     62
#define NV     14522
#define NCORE  28
#define KPAD   256    // 62*4 = 248 padded to 256
#define NN     768    // 256 batches * 3 rows
#define MPAD   14528  // ceil(NV/64)*64
#define OUTF   (NV * 3)          // 43566 floats per batch region
#define BM     64
#define BN     96                // 32 batches per block
#define REGW   196               // padded per-batch LDS stride (floats); 784B, 16B-aligned

typedef __attribute__((ext_vector_type(8))) short short8v;   // 8 bf16
typedef __attribute__((ext_vector_type(4))) short short4v;   // 4 bf16
typedef __attribute__((ext_vector_type(4))) float floatx4;
typedef __attribute__((ext_vector_type(2))) float floatx2;

static __device__ inline short f2bf(float x) {
    unsigned u = __float_as_uint(x);
    unsigned r = (u + 0x7fffu + ((u >> 16) & 1u)) >> 16;
    return (short)r;
}

// ---------------------------------------------------------------------------
// Kernel 1: per-batch forward kinematics. One block per batch, 64 threads.
// Writes J_out (fp32) and skinning transforms in bf16 GEMM-B layout:
//   Bt[(b*3+i)*KPAD + k*4+j] = G'[b,k,i,j],  G' = [Rg | tg - Rg*Jt]
// ---------------------------------------------------------------------------
__global__ __launch_bounds__(64) void fk_kernel(
    const float* __restrict__ thetas,   // (B, K*3)
    const float* __restrict__ blc,      // (B, NCORE)
    const float* __restrict__ cbl,      // (B, 1)
    const float* __restrict__ trans,    // (B, 3)
    const float* __restrict__ scale,    // (B,)
    const float* __restrict__ tpose,    // (K, 3)
    const int*   __restrict__ parents,  // (K,)
    const int*   __restrict__ mapper,   // (K,)
    short* __restrict__ Bt,             // (NN, KPAD) bf16
    float* __restrict__ Jout)           // (B, K, 3)
{
    __shared__ float Asm[NJ][12];
    __shared__ float Gsm[NJ][12];

    const int b = blockIdx.x;
    const int k = threadIdx.x;
    int p = 0;

    if (k < NJ) {
        p = parents[k];
        const float tz = thetas[(b * NJ + k) * 3 + 0];
        const float ty = thetas[(b * NJ + k) * 3 + 1];
        const float tx = thetas[(b * NJ + k) * 3 + 2];
        const float cx = cosf(tx), sx = sinf(tx);
        const float cy = cosf(ty), sy = sinf(ty);
        const float cz = cosf(tz), sz = sinf(tz);
        // R = Rz @ Ry @ Rx
        const float r00 = cz * cy;
        const float r01 = cz * sy * sx - sz * cx;
        const float r02 = sz * sx + cz * sy * cx;
        const float r10 = sz * cy;
        const float r11 = cz * cx + sz * sy * sx;
        const float r12 = sz * sy * cx - cz * sx;
        const float r20 = -sy;
        const float r21 = cy * sx;
        const float r22 = cy * cx;

        float f;
        const int m = mapper[k];
        if (k == 0)        f = 1.0f;
        else if (k == 1)   f = cbl[b];
        else if (m < 0)    f = 1.0f;
        else               f = 2.0f / (1.0f + expf(-blc[b * NCORE + m] * 0.2f));

        float ox, oy, oz;
        if (k == 0) {
            ox = tpose[0]; oy = tpose[1]; oz = tpose[2];
        } else {
            ox = (tpose[k * 3 + 0] - tpose[p * 3 + 0]) * f;
            oy = (tpose[k * 3 + 1] - tpose[p * 3 + 1]) * f;
            oz = (tpose[k * 3 + 2] - tpose[p * 3 + 2]) * f;
        }
        Asm[k][0] = r00; Asm[k][1] = r01; Asm[k][2]  = r02; Asm[k][3]  = ox;
        Asm[k][4] = r10; Asm[k][5] = r11; Asm[k][6]  = r12; Asm[k][7]  = oy;
        Asm[k][8] = r20; Asm[k][9] = r21; Asm[k][10] = r22; Asm[k][11] = oz;
    }
    __syncthreads();

    if (k == 0) {
        #pragma unroll
        for (int j = 0; j < 12; ++j) Gsm[0][j] = Asm[0][j];
    }
    __syncthreads();

    const int depth = (k < NJ) ? (31 - __clz((unsigned)(k + 1))) : 99;
    for (int d = 1; d <= 5; ++d) {
        if (depth == d) {
            float gp[12], a[12], g[12];
            #pragma unroll
            for (int j = 0; j < 12; ++j) { gp[j] = Gsm[p][j]; a[j] = Asm[k][j]; }
            #pragma unroll
            for (int i = 0; i < 3; ++i) {
                #pragma unroll
                for (int j = 0; j < 4; ++j) {
                    float s = (j == 3) ? gp[i * 4 + 3] : 0.0f;
                    s = fmaf(gp[i * 4 + 0], a[0 * 4 + j], s);
                    s = fmaf(gp[i * 4 + 1], a[1 * 4 + j], s);
                    s = fmaf(gp[i * 4 + 2], a[2 * 4 + j], s);
                    g[i * 4 + j] = s;
                }
            }
            #pragma unroll
            for (int j = 0; j < 12; ++j) Gsm[k][j] = g[j];
        }
        __syncthreads();
    }

    if (k < NJ) {
        float g[12];
        #pragma unroll
        for (int j = 0; j < 12; ++j) g[j] = Gsm[k][j];
        const float jx = tpose[k * 3 + 0];
        const float jy = tpose[k * 3 + 1];
        const float jz = tpose[k * 3 + 2];
        const float s  = scale[b];
        const float t0 = trans[b * 3 + 0], t1 = trans[b * 3 + 1], t2 = trans[b * 3 + 2];
        Jout[(b * NJ + k) * 3 + 0] = fmaf(g[3],  s, t0);
        Jout[(b * NJ + k) * 3 + 1] = fmaf(g[7],  s, t1);
        Jout[(b * NJ + k) * 3 + 2] = fmaf(g[11], s, t2);
        // t' = t - R * Jt
        float np[3];
        np[0] = g[3]  - (g[0] * jx + g[1] * jy + g[2]  * jz);
        np[1] = g[7]  - (g[4] * jx + g[5] * jy + g[6]  * jz);
        np[2] = g[11] - (g[8] * jx + g[9] * jy + g[10] * jz);

        #pragma unroll
        for (int i = 0; i < 3; ++i) {
            short4v o;
            o[0] = f2bf(g[i * 4 + 0]);
            o[1] = f2bf(g[i * 4 + 1]);
            o[2] = f2bf(g[i * 4 + 2]);
            o[3] = f2bf(np[i]);
            *(short4v*)&Bt[(size_t)(b * 3 + i) * KPAD + k * 4] = o;
        }
        if (k == 0) {  // zero K padding cols 248..255 for this batch's 3 rows
            short4v z = {0, 0, 0, 0};
            #pragma unroll
            for (int i = 0; i < 3; ++i) {
                *(short4v*)&Bt[(size_t)(b * 3 + i) * KPAD + 248] = z;
                *(short4v*)&Bt[(size_t)(b * 3 + i) * KPAD + 252] = z;
            }
        }
    }
}

// ---------------------------------------------------------------------------
// Kernel 2: build WH (MPAD, KPAD) bf16:  WH[v][4k+j] = w[v,k] * h_v[j].
// ---------------------------------------------------------------------------
__global__ __launch_bounds__(256) void build_wh(
    const float* __restrict__ W,      // (V, NJ)
    const float* __restrict__ vt,     // (V, 3)
    short* __restrict__ WH)
{
    const int id = blockIdx.x * 256 + threadIdx.x;   // MPAD*32 total
    const int v = id >> 5;
    const int c = id & 31;           // chunk: joints 2c, 2c+1
    const int k = c * 2;
    float w0 = 0.f, w1 = 0.f, hx = 0.f, hy = 0.f, hz = 0.f;
    if (v < NV) {
        hx = vt[v * 3 + 0]; hy = vt[v * 3 + 1]; hz = vt[v * 3 + 2];
        if (k < NJ)     w0 = W[(size_t)v * NJ + k];
        if (k + 1 < NJ) w1 = W[(size_t)v * NJ + k + 1];
    }
    short8v o;
    o[0] = f2bf(w0 * hx); o[1] = f2bf(w0 * hy); o[2] = f2bf(w0 * hz); o[3] = f2bf(w0);
    o[4] = f2bf(w1 * hx); o[5] = f2bf(w1 * hy); o[6] = f2bf(w1 * hz); o[7] = f2bf(w1);
    *(short8v*)&WH[(size_t)v * KPAD + c * 8] = o;
}

// ---------------------------------------------------------------------------
// Kernel 3: GEMM + epilogue.  OUT (MPAD x NN) = WH * Bt^T, then
// out[b, v*3+i] = OUT[v][3b+i]*scale[b] + trans[3b+i], written coalesced via
// an LDS transpose staged per-batch: lds[b_loc][m*3+i].
// Block: 256 thr (2x2 waves), tile BM=64 x BN=96 (32 batches). Grid (227, 8).
// ---------------------------------------------------------------------------
__global__ __launch_bounds__(256) void gemm_skin(
    const short* __restrict__ WH,     // (MPAD, KPAD) bf16
    const short* __restrict__ Bt,     // (NN, KPAD) bf16
    const float* __restrict__ scale,  // (B,)
    const float* __restrict__ trans,  // (B*3,)
    float* __restrict__ out)          // (B, V, 3)
{
    __shared__ float lds[32 * REGW];  // 25088 B

    const int wave = threadIdx.x >> 6;        // 0..3
    const int lane = threadIdx.x & 63;
    const int wm = wave >> 1, wn = wave & 1;  // 2x2 wave grid
    const int m0 = blockIdx.x * BM;
    const int mw = wm * 32;                   // wave m offset (block-local)
    const int nw = wn * 48;                   // wave n offset (block-local)
    const int lrow = lane & 15;
    const int lk8  = (lane >> 4) * 8;
    const int b0   = blockIdx.y * 32;         // first batch of this block

    floatx4 acc[2][3];
    #pragma unroll
    for (int mt = 0; mt < 2; ++mt)
        #pragma unroll
        for (int nt = 0; nt < 3; ++nt)
            acc[mt][nt] = (floatx4){0.f, 0.f, 0.f, 0.f};

    #pragma unroll
    for (int k0 = 0; k0 < KPAD; k0 += 32) {
        short8v a[2], bfr[3];
        #pragma unroll
        for (int mt = 0; mt < 2; ++mt)
            a[mt] = *(const short8v*)&WH[(size_t)(m0 + mw + mt * 16 + lrow) * KPAD + k0 + lk8];
        #pragma unroll
        for (int nt = 0; nt < 3; ++nt)
            bfr[nt] = *(const short8v*)&Bt[(size_t)(blockIdx.y * BN + nw + nt * 16 + lrow) * KPAD + k0 + lk8];
        #pragma unroll
        for (int mt = 0; mt < 2; ++mt)
            #pragma unroll
            for (int nt = 0; nt < 3; ++nt)
                acc[mt][nt] = __builtin_amdgcn_mfma_f32_16x16x32_bf16(
                    a[mt], bfr[nt], acc[mt][nt], 0, 0, 0);
    }

    // stage into LDS as [b_loc][m_loc*3 + i], applying scale/trans
    #pragma unroll
    for (int nt = 0; nt < 3; ++nt) {
        const int n_loc = nw + nt * 16 + lrow;        // 0..95
        const int b_loc = n_loc / 3;
        const int i     = n_loc - b_loc * 3;
        const int bg    = b0 + b_loc;
        const float s   = scale[bg];
        const float t   = trans[bg * 3 + i];
        #pragma unroll
        for (int mt = 0; mt < 2; ++mt) {
            const int m_loc = mw + mt * 16 + (lane >> 4) * 4;
            float* dst = &lds[b_loc * REGW + m_loc * 3 + i];
            #pragma unroll
            for (int r = 0; r < 4; ++r)
                dst[r * 3] = fmaf(acc[mt][nt][r], s, t);
        }
    }
    __syncthreads();

    // coalesced write-back: 32 regions x 192 floats = 3072 float2
    const bool edge = (m0 + BM) * 3 > OUTF;   // only the last m-block
    #pragma unroll
    for (int it = 0; it < 12; ++it) {
        const int idx   = it * 256 + threadIdx.x;     // 0..3071
        const int b_loc = idx / 96;
        const int rem   = idx - b_loc * 96;           // float2 index within region
        const floatx2 val = *(const floatx2*)&lds[b_loc * REGW + rem * 2];
        const size_t base = (size_t)(b0 + b_loc) * OUTF + (size_t)m0 * 3 + rem * 2;
        if (!edge) {
            *(floatx2*)&out[base] = val;
        } else {
            const int p = m0 * 3 + rem * 2;
            if (p + 1 < OUTF)      *(floatx2*)&out[base] = val;
            else if (p < OUTF)     out[base] = val[0];
        }
    }
}

extern "C" void kernel_launch(void* const* d_in, const int* in_sizes, int n_in,
                              void* d_out, int out_size, void* d_ws, size_t ws_size,
                              hipStream_t stream)
{
    const float* thetas  = (const float*)d_in[0];
    const float* blc     = (const float*)d_in[1];
    const float* cbl     = (const float*)d_in[2];
    const float* trans   = (const float*)d_in[3];
    const float* scale   = (const float*)d_in[4];
    const float* vtempl  = (const float*)d_in[5];
    const float* tpose   = (const float*)d_in[6];
    const float* weights = (const float*)d_in[7];
    const int*   parents = (const int*)d_in[8];
    const int*   mapper  = (const int*)d_in[9];

    float* out  = (float*)d_out;
    float* Jout = out + (size_t)NBATCH * NV * 3;

    short* WH = (short*)d_ws;                          // MPAD*KPAD bf16 = 7.44 MB
    short* Bt = WH + (size_t)MPAD * KPAD;              // NN*KPAD bf16 = 0.39 MB

    fk_kernel<<<NBATCH, 64, 0, stream>>>(thetas, blc, cbl, trans, scale, tpose,
                                         parents, mapper, Bt, Jout);
    build_wh<<<(MPAD * 32) / 256, 256, 0, stream>>>(weights, vtempl, WH);
    gemm_skin<<<dim3(MPAD / BM, NN / BN), 256, 0, stream>>>(
        WH, Bt, scale, trans, out);
}

// Round 4
// 38.920 us; speedup vs baseline: 2.7637x; 1.5525x over previous
//
#include <hip/hip_runtime.h>

#define NBATCH 256
#define NJ     62
#define NV     14522
#define NCORE  28
#define KPAD   256    // 62*4 = 248 padded to 256 (512 B per row)
#define NN     768    // 256 batches * 3 rows
#define MPAD   14528  // ceil(NV/64)*64
#define OUTF   (NV * 3)
#define BM     64
#define BN     96     // 32 batches per block
#define REGW   196    // padded per-batch LDS stride (floats)

typedef __attribute__((ext_vector_type(8))) short short8v;   // 8 bf16
typedef __attribute__((ext_vector_type(4))) short short4v;   // 4 bf16
typedef __attribute__((ext_vector_type(4))) float floatx4;
typedef __attribute__((ext_vector_type(2))) float floatx2;

#define AS1(p) ((const __attribute__((address_space(1))) void*)(p))
#define AS3(p) ((__attribute__((address_space(3))) void*)(p))

static __device__ inline short f2bf(float x) {
    unsigned u = __float_as_uint(x);
    unsigned r = (u + 0x7fffu + ((u >> 16) & 1u)) >> 16;
    return (short)r;
}

// XOR swizzle: spread the 16B chunks of a 512B row across banks by row&7.
// Involution; applied to the global SOURCE at staging and to LDS reads.
static __device__ inline unsigned swz(unsigned off) {
    return off ^ (((off >> 9) & 7u) << 4);
}

// ---------------------------------------------------------------------------
// Kernel 1 (fused prep):
//   blocks [0,64):   FK for 4 batches each (one per wave); writes Jout and
//                    Bt[(b*3+i)*KPAD + k*4+j] = G' bf16 (GEMM-B layout)
//   blocks [64, ..): build WH[v][4k+j] = w[v,k]*h_v[j] bf16
// ---------------------------------------------------------------------------
__global__ __launch_bounds__(256) void prep_kernel(
    const float* __restrict__ thetas, const float* __restrict__ blc,
    const float* __restrict__ cbl, const float* __restrict__ trans,
    const float* __restrict__ scale, const float* __restrict__ tpose,
    const int* __restrict__ parents, const int* __restrict__ mapper,
    const float* __restrict__ W, const float* __restrict__ vt,
    short* __restrict__ Bt, short* __restrict__ WH,
    float* __restrict__ Jout)
{
    __shared__ float Asm[4][NJ][12];
    __shared__ float Gsm[4][NJ][12];

    if (blockIdx.x >= 64) {
        // ---- build_wh role
        const int id = (blockIdx.x - 64) * 256 + threadIdx.x;  // MPAD*32 total
        const int v = id >> 5;
        const int c = id & 31;             // chunk: joints 2c, 2c+1
        const int k = c * 2;
        float w0 = 0.f, w1 = 0.f, hx = 0.f, hy = 0.f, hz = 0.f;
        if (v < NV) {
            hx = vt[v * 3 + 0]; hy = vt[v * 3 + 1]; hz = vt[v * 3 + 2];
            if (k < NJ)     w0 = W[(size_t)v * NJ + k];
            if (k + 1 < NJ) w1 = W[(size_t)v * NJ + k + 1];
        }
        short8v o;
        o[0] = f2bf(w0 * hx); o[1] = f2bf(w0 * hy); o[2] = f2bf(w0 * hz); o[3] = f2bf(w0);
        o[4] = f2bf(w1 * hx); o[5] = f2bf(w1 * hy); o[6] = f2bf(w1 * hz); o[7] = f2bf(w1);
        if (v < MPAD) *(short8v*)&WH[(size_t)v * KPAD + c * 8] = o;
        return;
    }

    // ---- FK role: wave w handles batch b
    const int w = threadIdx.x >> 6;
    const int b = blockIdx.x * 4 + w;
    const int k = threadIdx.x & 63;
    int p = 0;

    if (k < NJ) {
        p = parents[k];
        const float tz = thetas[(b * NJ + k) * 3 + 0];
        const float ty = thetas[(b * NJ + k) * 3 + 1];
        const float tx = thetas[(b * NJ + k) * 3 + 2];
        const float cx = cosf(tx), sx = sinf(tx);
        const float cy = cosf(ty), sy = sinf(ty);
        const float cz = cosf(tz), sz = sinf(tz);
        const float r00 = cz * cy;
        const float r01 = cz * sy * sx - sz * cx;
        const float r02 = sz * sx + cz * sy * cx;
        const float r10 = sz * cy;
        const float r11 = cz * cx + sz * sy * sx;
        const float r12 = sz * sy * cx - cz * sx;
        const float r20 = -sy;
        const float r21 = cy * sx;
        const float r22 = cy * cx;

        float f;
        const int m = mapper[k];
        if (k == 0)        f = 1.0f;
        else if (k == 1)   f = cbl[b];
        else if (m < 0)    f = 1.0f;
        else               f = 2.0f / (1.0f + expf(-blc[b * NCORE + m] * 0.2f));

        float ox, oy, oz;
        if (k == 0) {
            ox = tpose[0]; oy = tpose[1]; oz = tpose[2];
        } else {
            ox = (tpose[k * 3 + 0] - tpose[p * 3 + 0]) * f;
            oy = (tpose[k * 3 + 1] - tpose[p * 3 + 1]) * f;
            oz = (tpose[k * 3 + 2] - tpose[p * 3 + 2]) * f;
        }
        Asm[w][k][0] = r00; Asm[w][k][1] = r01; Asm[w][k][2]  = r02; Asm[w][k][3]  = ox;
        Asm[w][k][4] = r10; Asm[w][k][5] = r11; Asm[w][k][6]  = r12; Asm[w][k][7]  = oy;
        Asm[w][k][8] = r20; Asm[w][k][9] = r21; Asm[w][k][10] = r22; Asm[w][k][11] = oz;
    }
    __syncthreads();

    if (k == 0) {
        #pragma unroll
        for (int j = 0; j < 12; ++j) Gsm[w][0][j] = Asm[w][0][j];
    }
    __syncthreads();

    const int depth = (k < NJ) ? (31 - __clz((unsigned)(k + 1))) : 99;
    for (int d = 1; d <= 5; ++d) {
        if (depth == d) {
            float gp[12], a[12], g[12];
            #pragma unroll
            for (int j = 0; j < 12; ++j) { gp[j] = Gsm[w][p][j]; a[j] = Asm[w][k][j]; }
            #pragma unroll
            for (int i = 0; i < 3; ++i) {
                #pragma unroll
                for (int j = 0; j < 4; ++j) {
                    float s = (j == 3) ? gp[i * 4 + 3] : 0.0f;
                    s = fmaf(gp[i * 4 + 0], a[0 * 4 + j], s);
                    s = fmaf(gp[i * 4 + 1], a[1 * 4 + j], s);
                    s = fmaf(gp[i * 4 + 2], a[2 * 4 + j], s);
                    g[i * 4 + j] = s;
                }
            }
            #pragma unroll
            for (int j = 0; j < 12; ++j) Gsm[w][k][j] = g[j];
        }
        __syncthreads();
    }

    if (k < NJ) {
        float g[12];
        #pragma unroll
        for (int j = 0; j < 12; ++j) g[j] = Gsm[w][k][j];
        const float jx = tpose[k * 3 + 0];
        const float jy = tpose[k * 3 + 1];
        const float jz = tpose[k * 3 + 2];
        const float s  = scale[b];
        Jout[(b * NJ + k) * 3 + 0] = fmaf(g[3],  s, trans[b * 3 + 0]);
        Jout[(b * NJ + k) * 3 + 1] = fmaf(g[7],  s, trans[b * 3 + 1]);
        Jout[(b * NJ + k) * 3 + 2] = fmaf(g[11], s, trans[b * 3 + 2]);
        float np[3];
        np[0] = g[3]  - (g[0] * jx + g[1] * jy + g[2]  * jz);
        np[1] = g[7]  - (g[4] * jx + g[5] * jy + g[6]  * jz);
        np[2] = g[11] - (g[8] * jx + g[9] * jy + g[10] * jz);
        #pragma unroll
        for (int i = 0; i < 3; ++i) {
            short4v o;
            o[0] = f2bf(g[i * 4 + 0]);
            o[1] = f2bf(g[i * 4 + 1]);
            o[2] = f2bf(g[i * 4 + 2]);
            o[3] = f2bf(np[i]);
            *(short4v*)&Bt[(size_t)(b * 3 + i) * KPAD + k * 4] = o;
        }
        if (k == 0) {  // zero K padding cols 248..255
            short4v z = {0, 0, 0, 0};
            #pragma unroll
            for (int i = 0; i < 3; ++i) {
                *(short4v*)&Bt[(size_t)(b * 3 + i) * KPAD + 248] = z;
                *(short4v*)&Bt[(size_t)(b * 3 + i) * KPAD + 252] = z;
            }
        }
    }
}

// ---------------------------------------------------------------------------
// Kernel 2: GEMM + epilogue.  OUT (MPAD x NN) = WH * Bt^T.
// 512 threads = 8 waves (4m x 2n); tile BM=64 x BN=96; full-K LDS staging
// via global_load_lds (A 32KB + B 48KB, XOR-swizzled), then 24 MFMA/wave,
// then coalesced store through LDS transpose (reusing the B region).
// ---------------------------------------------------------------------------
__global__ __launch_bounds__(512) void gemm_skin(
    const short* __restrict__ WH,     // (MPAD, KPAD) bf16
    const short* __restrict__ Bt,     // (NN, KPAD) bf16
    const float* __restrict__ scale,  // (B,)
    const float* __restrict__ trans,  // (B*3,)
    float* __restrict__ out)          // (B, V, 3)
{
    __shared__ char lds_raw[32768 + 49152];          // 80 KB -> 2 blocks/CU
    short* ldsA = (short*)lds_raw;
    short* ldsB = (short*)(lds_raw + 32768);
    float* ldsE = (float*)(lds_raw + 32768);         // epilogue reuses B region

    const int tid  = threadIdx.x;
    const int wave = tid >> 6;        // 0..7
    const int lane = tid & 63;
    const int wm   = wave & 3;        // 4 m-waves of 16 rows
    const int wn   = wave >> 2;       // 2 n-waves of 48 cols
    const int m0   = blockIdx.x * BM;
    const int n0g  = blockIdx.y * BN;
    const int b0   = blockIdx.y * 32;
    const int lrow = lane & 15;
    const int lk   = lane >> 4;       // 0..3

    // ---- stage A (32KB) and B (48KB): linear LDS dest, inverse-swizzled src
    const char* Abase = (const char*)(WH + (size_t)m0 * KPAD);
    const char* Bbase = (const char*)(Bt + (size_t)n0g * KPAD);
    #pragma unroll
    for (int c = 0; c < 4; ++c) {
        const unsigned Lb = wave * 4096 + c * 1024;   // wave-uniform dest
        const unsigned L  = Lb + lane * 16;
        __builtin_amdgcn_global_load_lds(AS1(Abase + swz(L)),
                                         AS3((char*)ldsA + Lb), 16, 0, 0);
    }
    #pragma unroll
    for (int c = 0; c < 6; ++c) {
        const unsigned Lb = wave * 6144 + c * 1024;
        const unsigned L  = Lb + lane * 16;
        __builtin_amdgcn_global_load_lds(AS1(Bbase + swz(L)),
                                         AS3((char*)ldsB + Lb), 16, 0, 0);
    }
    __syncthreads();

    // ---- MFMA off LDS (swizzled reads)
    floatx4 acc[3];
    #pragma unroll
    for (int nt = 0; nt < 3; ++nt) acc[nt] = (floatx4){0.f, 0.f, 0.f, 0.f};

    const unsigned arow  = wm * 16 + lrow;
    const unsigned abase = arow * 512;
    const unsigned axor  = (arow & 7u) << 4;

    #pragma unroll
    for (int k8 = 0; k8 < 32; k8 += 4) {
        const unsigned kb16 = (unsigned)(k8 + lk) * 16;
        const short8v a = *(const short8v*)((const char*)ldsA + abase + (kb16 ^ axor));
        #pragma unroll
        for (int nt = 0; nt < 3; ++nt) {
            const unsigned brow = wn * 48 + nt * 16 + lrow;
            const short8v bf = *(const short8v*)((const char*)ldsB + brow * 512
                                                 + (kb16 ^ ((brow & 7u) << 4)));
            acc[nt] = __builtin_amdgcn_mfma_f32_16x16x32_bf16(a, bf, acc[nt], 0, 0, 0);
        }
    }
    __syncthreads();   // all ldsB reads done before ldsE overwrite

    // ---- stage output tile into LDS as [b_loc][m_loc*3+i] with scale/trans
    #pragma unroll
    for (int nt = 0; nt < 3; ++nt) {
        const int n_loc = wn * 48 + nt * 16 + lrow;   // 0..95
        const int b_loc = n_loc / 3;
        const int i     = n_loc - b_loc * 3;
        const int bg    = b0 + b_loc;
        const float s   = scale[bg];
        const float t   = trans[bg * 3 + i];
        const int m_loc = wm * 16 + lk * 4;
        float* dst = &ldsE[b_loc * REGW + m_loc * 3 + i];
        #pragma unroll
        for (int r = 0; r < 4; ++r)
            dst[r * 3] = fmaf(acc[nt][r], s, t);
    }
    __syncthreads();

    // ---- coalesced write-back: 32 regions x 96 float2 = 3072 float2
    const bool edge = (m0 + BM) * 3 > OUTF;
    #pragma unroll
    for (int it = 0; it < 6; ++it) {
        const int idx   = it * 512 + tid;             // 0..3071
        const int b_loc = idx / 96;
        const int rem   = idx - b_loc * 96;
        const floatx2 val = *(const floatx2*)&ldsE[b_loc * REGW + rem * 2];
        const size_t base = (size_t)(b0 + b_loc) * OUTF + (size_t)m0 * 3 + rem * 2;
        if (!edge) {
            *(floatx2*)&out[base] = val;
        } else {
            const int p = m0 * 3 + rem * 2;
            if (p + 1 < OUTF)      *(floatx2*)&out[base] = val;
            else if (p < OUTF)     out[base] = val[0];
        }
    }
}

extern "C" void kernel_launch(void* const* d_in, const int* in_sizes, int n_in,
                              void* d_out, int out_size, void* d_ws, size_t ws_size,
                              hipStream_t stream)
{
    const float* thetas  = (const float*)d_in[0];
    const float* blc     = (const float*)d_in[1];
    const float* cbl     = (const float*)d_in[2];
    const float* trans   = (const float*)d_in[3];
    const float* scale   = (const float*)d_in[4];
    const float* vtempl  = (const float*)d_in[5];
    const float* tpose   = (const float*)d_in[6];
    const float* weights = (const float*)d_in[7];
    const int*   parents = (const int*)d_in[8];
    const int*   mapper  = (const int*)d_in[9];

    float* out  = (float*)d_out;
    float* Jout = out + (size_t)NBATCH * NV * 3;

    short* WH = (short*)d_ws;                          // MPAD*KPAD bf16 = 7.44 MB
    short* Bt = WH + (size_t)MPAD * KPAD;              // NN*KPAD bf16 = 0.39 MB

    prep_kernel<<<64 + (MPAD * 32) / 256, 256, 0, stream>>>(
        thetas, blc, cbl, trans, scale, tpose, parents, mapper,
        weights, vtempl, Bt, WH, Jout);
    gemm_skin<<<dim3(MPAD / BM, NN / BN), 512, 0, stream>>>(
        WH, Bt, scale, trans, out);
}

// Round 5
// 29.814 us; speedup vs baseline: 3.6077x; 1.3054x over previous
//
#include <hip/hip_runtime.h>

#define NBATCH 256
#define NJ     62
#define NV     14522
#define NCORE  28
#define KPAD   256    // 62*4 = 248 padded to 256 (512 B per row)
#define NN     768    // 256 batches * 3 rows
#define MPAD   14528
#define OUTF   (NV * 3)
#define BMT    32     // gemm tile rows
#define XT     (MPAD / BMT)   // 454 x-tiles
#define BN     96     // 32 batches per y-group
#define EREGW  100    // epilogue LDS region stride (floats)

typedef __attribute__((ext_vector_type(8))) short short8v;
typedef __attribute__((ext_vector_type(4))) short short4v;
typedef __attribute__((ext_vector_type(4))) float floatx4;
typedef __attribute__((ext_vector_type(2))) float floatx2;

#define AS1(p) ((const __attribute__((address_space(1))) void*)(p))
#define AS3(p) ((__attribute__((address_space(3))) void*)(p))

#define SCHED0() __builtin_amdgcn_sched_barrier(0)
#define WAITVM(n) do { SCHED0(); asm volatile("s_waitcnt vmcnt(" #n ")" ::: "memory"); SCHED0(); } while (0)
#define WAITLGKM() do { SCHED0(); asm volatile("s_waitcnt lgkmcnt(0)" ::: "memory"); SCHED0(); } while (0)

static __device__ inline short f2bf(float x) {
    unsigned u = __float_as_uint(x);
    unsigned r = (u + 0x7fffu + ((u >> 16) & 1u)) >> 16;
    return (short)r;
}

// XOR swizzle over 512B rows: involution, applied to global SOURCE at staging
// and to LDS read addresses (both-sides rule).
static __device__ inline unsigned swz(unsigned off) {
    return off ^ (((off >> 9) & 7u) << 4);
}

// ---------------------------------------------------------------------------
// Kernel 1 (fused prep): blocks [0,64) = FK (4 batches/block, 1 per wave);
// blocks [64,..) = build WH[v][4k+j] = w[v,k]*h_v[j] (bf16).
// ---------------------------------------------------------------------------
__global__ __launch_bounds__(256) void prep_kernel(
    const float* __restrict__ thetas, const float* __restrict__ blc,
    const float* __restrict__ cbl, const float* __restrict__ trans,
    const float* __restrict__ scale, const float* __restrict__ tpose,
    const int* __restrict__ parents, const int* __restrict__ mapper,
    const float* __restrict__ W, const float* __restrict__ vt,
    short* __restrict__ Bt, short* __restrict__ WH,
    float* __restrict__ Jout)
{
    __shared__ float Asm[4][NJ][12];
    __shared__ float Gsm[4][NJ][12];

    if (blockIdx.x >= 64) {
        const int id = (blockIdx.x - 64) * 256 + threadIdx.x;
        const int v = id >> 5;
        const int c = id & 31;
        const int k = c * 2;
        float w0 = 0.f, w1 = 0.f, hx = 0.f, hy = 0.f, hz = 0.f;
        if (v < NV) {
            hx = vt[v * 3 + 0]; hy = vt[v * 3 + 1]; hz = vt[v * 3 + 2];
            if (k < NJ)     w0 = W[(size_t)v * NJ + k];
            if (k + 1 < NJ) w1 = W[(size_t)v * NJ + k + 1];
        }
        short8v o;
        o[0] = f2bf(w0 * hx); o[1] = f2bf(w0 * hy); o[2] = f2bf(w0 * hz); o[3] = f2bf(w0);
        o[4] = f2bf(w1 * hx); o[5] = f2bf(w1 * hy); o[6] = f2bf(w1 * hz); o[7] = f2bf(w1);
        if (v < MPAD) *(short8v*)&WH[(size_t)v * KPAD + c * 8] = o;
        return;
    }

    const int w = threadIdx.x >> 6;
    const int b = blockIdx.x * 4 + w;
    const int k = threadIdx.x & 63;
    int p = 0;

    if (k < NJ) {
        p = parents[k];
        const float tz = thetas[(b * NJ + k) * 3 + 0];
        const float ty = thetas[(b * NJ + k) * 3 + 1];
        const float tx = thetas[(b * NJ + k) * 3 + 2];
        const float cx = cosf(tx), sx = sinf(tx);
        const float cy = cosf(ty), sy = sinf(ty);
        const float cz = cosf(tz), sz = sinf(tz);
        const float r00 = cz * cy;
        const float r01 = cz * sy * sx - sz * cx;
        const float r02 = sz * sx + cz * sy * cx;
        const float r10 = sz * cy;
        const float r11 = cz * cx + sz * sy * sx;
        const float r12 = sz * sy * cx - cz * sx;
        const float r20 = -sy;
        const float r21 = cy * sx;
        const float r22 = cy * cx;

        float f;
        const int m = mapper[k];
        if (k == 0)        f = 1.0f;
        else if (k == 1)   f = cbl[b];
        else if (m < 0)    f = 1.0f;
        else               f = 2.0f / (1.0f + expf(-blc[b * NCORE + m] * 0.2f));

        float ox, oy, oz;
        if (k == 0) {
            ox = tpose[0]; oy = tpose[1]; oz = tpose[2];
        } else {
            ox = (tpose[k * 3 + 0] - tpose[p * 3 + 0]) * f;
            oy = (tpose[k * 3 + 1] - tpose[p * 3 + 1]) * f;
            oz = (tpose[k * 3 + 2] - tpose[p * 3 + 2]) * f;
        }
        Asm[w][k][0] = r00; Asm[w][k][1] = r01; Asm[w][k][2]  = r02; Asm[w][k][3]  = ox;
        Asm[w][k][4] = r10; Asm[w][k][5] = r11; Asm[w][k][6]  = r12; Asm[w][k][7]  = oy;
        Asm[w][k][8] = r20; Asm[w][k][9] = r21; Asm[w][k][10] = r22; Asm[w][k][11] = oz;
    }
    __syncthreads();

    if (k == 0) {
        #pragma unroll
        for (int j = 0; j < 12; ++j) Gsm[w][0][j] = Asm[w][0][j];
    }
    __syncthreads();

    const int depth = (k < NJ) ? (31 - __clz((unsigned)(k + 1))) : 99;
    for (int d = 1; d <= 5; ++d) {
        if (depth == d) {
            float gp[12], a[12], g[12];
            #pragma unroll
            for (int j = 0; j < 12; ++j) { gp[j] = Gsm[w][p][j]; a[j] = Asm[w][k][j]; }
            #pragma unroll
            for (int i = 0; i < 3; ++i) {
                #pragma unroll
                for (int j = 0; j < 4; ++j) {
                    float s = (j == 3) ? gp[i * 4 + 3] : 0.0f;
                    s = fmaf(gp[i * 4 + 0], a[0 * 4 + j], s);
                    s = fmaf(gp[i * 4 + 1], a[1 * 4 + j], s);
                    s = fmaf(gp[i * 4 + 2], a[2 * 4 + j], s);
                    g[i * 4 + j] = s;
                }
            }
            #pragma unroll
            for (int j = 0; j < 12; ++j) Gsm[w][k][j] = g[j];
        }
        __syncthreads();
    }

    if (k < NJ) {
        float g[12];
        #pragma unroll
        for (int j = 0; j < 12; ++j) g[j] = Gsm[w][k][j];
        const float jx = tpose[k * 3 + 0];
        const float jy = tpose[k * 3 + 1];
        const float jz = tpose[k * 3 + 2];
        const float s  = scale[b];
        Jout[(b * NJ + k) * 3 + 0] = fmaf(g[3],  s, trans[b * 3 + 0]);
        Jout[(b * NJ + k) * 3 + 1] = fmaf(g[7],  s, trans[b * 3 + 1]);
        Jout[(b * NJ + k) * 3 + 2] = fmaf(g[11], s, trans[b * 3 + 2]);
        float np[3];
        np[0] = g[3]  - (g[0] * jx + g[1] * jy + g[2]  * jz);
        np[1] = g[7]  - (g[4] * jx + g[5] * jy + g[6]  * jz);
        np[2] = g[11] - (g[8] * jx + g[9] * jy + g[10] * jz);
        #pragma unroll
        for (int i = 0; i < 3; ++i) {
            short4v o;
            o[0] = f2bf(g[i * 4 + 0]);
            o[1] = f2bf(g[i * 4 + 1]);
            o[2] = f2bf(g[i * 4 + 2]);
            o[3] = f2bf(np[i]);
            *(short4v*)&Bt[(size_t)(b * 3 + i) * KPAD + k * 4] = o;
        }
        if (k == 0) {
            short4v z = {0, 0, 0, 0};
            #pragma unroll
            for (int i = 0; i < 3; ++i) {
                *(short4v*)&Bt[(size_t)(b * 3 + i) * KPAD + 248] = z;
                *(short4v*)&Bt[(size_t)(b * 3 + i) * KPAD + 252] = z;
            }
        }
    }
}

// ---------------------------------------------------------------------------
// Kernel 2: persistent GEMM + epilogue. Grid 512 blocks x 256 thr (4 waves).
// Block (c = bid&63, y = bid>>6): B tile (96 rows) resident in LDS; loops
// x-tiles (BM=32) with A double-buffer + counted vmcnt pipeline. Epilogue
// reuses the consumed A buffer as transpose staging for coalesced stores.
// ---------------------------------------------------------------------------
__global__ __launch_bounds__(256) void gemm_skin(
    const short* __restrict__ WH,     // (MPAD, KPAD) bf16
    const short* __restrict__ Bt,     // (NN, KPAD) bf16
    const float* __restrict__ scale,  // (B,)
    const float* __restrict__ trans,  // (B*3,)
    float* __restrict__ out)          // (B, V, 3)
{
    __shared__ __align__(16) char lds_raw[49152 + 2 * 16384];   // 80 KB
    char* A0 = lds_raw + 49152;
    char* A1 = lds_raw + 49152 + 16384;

    const int tid  = threadIdx.x;
    const int wave = tid >> 6;
    const int lane = tid & 63;
    const int lrow = lane & 15;
    const int lk   = lane >> 4;
    const int c    = blockIdx.x & 63;       // x-stripe
    const int y    = blockIdx.x >> 6;       // batch group
    const int b0   = y * 32;
    const int ntiles = (XT - c + 63) >> 6;  // 7 or 8
    const int wm = wave & 1, wn = wave >> 1;

    // ---- prologue: stage B (48KB, resident) + A tile 0 (16KB)
    {
        const char* Bbase = (const char*)(Bt + (size_t)y * BN * KPAD);
        #pragma unroll
        for (int cc = 0; cc < 12; ++cc) {
            const unsigned Lb = wave * 12288 + cc * 1024;
            __builtin_amdgcn_global_load_lds(AS1(Bbase + swz(Lb + lane * 16)),
                                             AS3(lds_raw + Lb), 16, 0, 0);
        }
        const char* Abase = (const char*)(WH + (size_t)c * BMT * KPAD);
        #pragma unroll
        for (int cc = 0; cc < 4; ++cc) {
            const unsigned Lb = wave * 4096 + cc * 1024;
            __builtin_amdgcn_global_load_lds(AS1(Abase + swz(Lb + lane * 16)),
                                             AS3(A0 + Lb), 16, 0, 0);
        }
    }

    // ---- hoisted per-thread invariants
    int   ereg[3], eoff[3];
    float sv[3], tv[3];
    #pragma unroll
    for (int nt = 0; nt < 3; ++nt) {
        const int n_loc = wn * 48 + nt * 16 + lrow;
        const int b_loc = n_loc / 3;
        const int i     = n_loc - b_loc * 3;
        ereg[nt] = b_loc;
        eoff[nt] = i;
        sv[nt] = scale[b0 + b_loc];
        tv[nt] = trans[(b0 + b_loc) * 3 + i];
    }
    size_t wb_base[6]; int wb_lds[6], wb_rem[6];
    #pragma unroll
    for (int it2 = 0; it2 < 6; ++it2) {
        const int idx = it2 * 256 + tid;      // 0..1535 (float2 units)
        const int bl  = idx / 48;
        const int rem2 = (idx - bl * 48) * 2; // float offset in region
        wb_base[it2] = (size_t)(b0 + bl) * OUTF + rem2;
        wb_lds[it2]  = bl * EREGW + rem2;
        wb_rem[it2]  = rem2;
    }
    const unsigned abase = (wm * 16 + lrow) * 512;
    const unsigned axor  = ((wm * 16 + lrow) & 7u) << 4;
    unsigned bofs[3], bxor[3];
    #pragma unroll
    for (int nt = 0; nt < 3; ++nt) {
        const unsigned brow = wn * 48 + nt * 16 + lrow;
        bofs[nt] = brow * 512;
        bxor[nt] = (brow & 7u) << 4;
    }

    WAITVM(0);
    __builtin_amdgcn_s_barrier();
    SCHED0();

    for (int t = 0; t < ntiles; ++t) {
        const int x = c + (t << 6);
        char* bufR = (t & 1) ? A1 : A0;

        // 1. issue next A DMA into the other buffer (prev barrier guarantees
        //    all writeback reads of that buffer are complete)
        if (t + 1 < ntiles) {
            char* bufW = (t & 1) ? A0 : A1;
            const char* src = (const char*)(WH + (size_t)(x + 64) * BMT * KPAD);
            #pragma unroll
            for (int cc = 0; cc < 4; ++cc) {
                const unsigned Lb = wave * 4096 + cc * 1024;
                __builtin_amdgcn_global_load_lds(AS1(src + swz(Lb + lane * 16)),
                                                 AS3(bufW + Lb), 16, 0, 0);
            }
            // outstanding: A[t](4, oldest) .. stores(6) .. A[t+1](4):
            // vmcnt(10) <=> A[t] retired; never drains the new DMA/stores.
            WAITVM(10);
        } else {
            WAITVM(6);   // outstanding: A[t](4) + stores(6) -> wait A[t] only
        }
        __builtin_amdgcn_s_barrier();   // all waves' A[t] chunks landed
        SCHED0();

        // 2. MFMA off LDS (swizzled reads)
        floatx4 acc[3];
        #pragma unroll
        for (int nt = 0; nt < 3; ++nt) acc[nt] = (floatx4){0.f, 0.f, 0.f, 0.f};
        #pragma unroll
        for (int k8 = 0; k8 < 8; ++k8) {
            const unsigned kb16 = (unsigned)(k8 * 4 + lk) * 16;
            const short8v a = *(const short8v*)(bufR + abase + (kb16 ^ axor));
            #pragma unroll
            for (int nt = 0; nt < 3; ++nt) {
                const short8v bf = *(const short8v*)(lds_raw + bofs[nt] + (kb16 ^ bxor[nt]));
                acc[nt] = __builtin_amdgcn_mfma_f32_16x16x32_bf16(a, bf, acc[nt], 0, 0, 0);
            }
        }
        SCHED0();
        __builtin_amdgcn_s_barrier();   // all reads of bufR consumed
        SCHED0();

        // 3. epilogue transpose into bufR: [b_loc][m_loc*3+i], scale/trans applied
        float* ldsE = (float*)bufR;
        #pragma unroll
        for (int nt = 0; nt < 3; ++nt) {
            const int mbase = wm * 16 + lk * 4;
            float* dst = &ldsE[ereg[nt] * EREGW + mbase * 3 + eoff[nt]];
            #pragma unroll
            for (int r = 0; r < 4; ++r)
                dst[r * 3] = fmaf(acc[nt][r], sv[nt], tv[nt]);
        }
        WAITLGKM();
        __builtin_amdgcn_s_barrier();   // epi writes visible
        SCHED0();

        // 4. coalesced write-back: 32 regions x 48 float2
        const int m0f = x * 96;
        const bool edge = m0f + 96 > OUTF;   // only x == XT-1
        #pragma unroll
        for (int it2 = 0; it2 < 6; ++it2) {
            const floatx2 val = *(const floatx2*)&ldsE[wb_lds[it2]];
            const size_t base = wb_base[it2] + m0f;
            if (!edge) {
                *(floatx2*)&out[base] = val;
            } else {
                const int p = m0f + wb_rem[it2];
                if (p + 1 < OUTF)      *(floatx2*)&out[base] = val;
                else if (p < OUTF)     out[base] = val[0];
            }
        }

        // 5. fence before next iteration's DMA reuses this buffer
        if (t + 1 < ntiles) {
            SCHED0();
            __builtin_amdgcn_s_barrier();
            SCHED0();
        }
    }
}

extern "C" void kernel_launch(void* const* d_in, const int* in_sizes, int n_in,
                              void* d_out, int out_size, void* d_ws, size_t ws_size,
                              hipStream_t stream)
{
    const float* thetas  = (const float*)d_in[0];
    const float* blc     = (const float*)d_in[1];
    const float* cbl     = (const float*)d_in[2];
    const float* trans   = (const float*)d_in[3];
    const float* scale   = (const float*)d_in[4];
    const float* vtempl  = (const float*)d_in[5];
    const float* tpose   = (const float*)d_in[6];
    const float* weights = (const float*)d_in[7];
    const int*   parents = (const int*)d_in[8];
    const int*   mapper  = (const int*)d_in[9];

    float* out  = (float*)d_out;
    float* Jout = out + (size_t)NBATCH * NV * 3;

    short* WH = (short*)d_ws;                          // MPAD*KPAD bf16 = 7.44 MB
    short* Bt = WH + (size_t)MPAD * KPAD;              // NN*KPAD bf16 = 0.39 MB

    prep_kernel<<<64 + (MPAD * 32) / 256, 256, 0, stream>>>(
        thetas, blc, cbl, trans, scale, tpose, parents, mapper,
        weights, vtempl, Bt, WH, Jout);
    gemm_skin<<<512, 256, 0, stream>>>(WH, Bt, scale, trans, out);
}

// Round 6
// 28.949 us; speedup vs baseline: 3.7155x; 1.0299x over previous
//
#include <hip/hip_runtime.h>

#define NBATCH 256
#define NJ     62
#define NV     14522
#define NCORE  28
#define KPAD   256    // 62*4 = 248 padded to 256 (512 B per row)
#define NN     768
#define MPAD   14528
#define OUTF   (NV * 3)        // 43566
#define MT     908             // m-tiles of 16 rows (MPAD/16)
#define NSTRIPE 128            // wave stripes; tiles = s + 128*t

typedef __attribute__((ext_vector_type(8))) short short8v;
typedef __attribute__((ext_vector_type(4))) short short4v;
typedef __attribute__((ext_vector_type(4))) float floatx4;
typedef __attribute__((ext_vector_type(2))) float floatx2;

#define AS1(p) ((const __attribute__((address_space(1))) void*)(p))
#define AS3(p) ((__attribute__((address_space(3))) void*)(p))

#define SCHED0() __builtin_amdgcn_sched_barrier(0)
#define WAITVM(n) do { SCHED0(); asm volatile("s_waitcnt vmcnt(" #n ")" ::: "memory"); SCHED0(); } while (0)

static __device__ inline short f2bf(float x) {
    unsigned u = __float_as_uint(x);
    unsigned r = (u + 0x7fffu + ((u >> 16) & 1u)) >> 16;
    return (short)r;
}

// XOR swizzle over 512B rows: involution; applied to global SOURCE at staging
// and to LDS read addresses.
static __device__ inline unsigned swz(unsigned off) {
    return off ^ (((off >> 9) & 7u) << 4);
}

// ---------------------------------------------------------------------------
// Kernel 1 (fused prep): blocks [0,64) = FK (4 batches/block, 1 per wave);
// blocks [64,..) = build WH[v][4k+j] = w[v,k]*h_v[j] (bf16).
// ---------------------------------------------------------------------------
__global__ __launch_bounds__(256) void prep_kernel(
    const float* __restrict__ thetas, const float* __restrict__ blc,
    const float* __restrict__ cbl, const float* __restrict__ trans,
    const float* __restrict__ scale, const float* __restrict__ tpose,
    const int* __restrict__ parents, const int* __restrict__ mapper,
    const float* __restrict__ W, const float* __restrict__ vt,
    short* __restrict__ Bt, short* __restrict__ WH,
    float* __restrict__ Jout)
{
    __shared__ float Asm[4][NJ][12];
    __shared__ float Gsm[4][NJ][12];

    if (blockIdx.x >= 64) {
        const int id = (blockIdx.x - 64) * 256 + threadIdx.x;
        const int v = id >> 5;
        const int c = id & 31;
        const int k = c * 2;
        float w0 = 0.f, w1 = 0.f, hx = 0.f, hy = 0.f, hz = 0.f;
        if (v < NV) {
            hx = vt[v * 3 + 0]; hy = vt[v * 3 + 1]; hz = vt[v * 3 + 2];
            if (k < NJ)     w0 = W[(size_t)v * NJ + k];
            if (k + 1 < NJ) w1 = W[(size_t)v * NJ + k + 1];
        }
        short8v o;
        o[0] = f2bf(w0 * hx); o[1] = f2bf(w0 * hy); o[2] = f2bf(w0 * hz); o[3] = f2bf(w0);
        o[4] = f2bf(w1 * hx); o[5] = f2bf(w1 * hy); o[6] = f2bf(w1 * hz); o[7] = f2bf(w1);
        if (v < MPAD) *(short8v*)&WH[(size_t)v * KPAD + c * 8] = o;
        return;
    }

    const int w = threadIdx.x >> 6;
    const int b = blockIdx.x * 4 + w;
    const int k = threadIdx.x & 63;
    int p = 0;

    if (k < NJ) {
        p = parents[k];
        const float tz = thetas[(b * NJ + k) * 3 + 0];
        const float ty = thetas[(b * NJ + k) * 3 + 1];
        const float tx = thetas[(b * NJ + k) * 3 + 2];
        const float cx = cosf(tx), sx = sinf(tx);
        const float cy = cosf(ty), sy = sinf(ty);
        const float cz = cosf(tz), sz = sinf(tz);
        const float r00 = cz * cy;
        const float r01 = cz * sy * sx - sz * cx;
        const float r02 = sz * sx + cz * sy * cx;
        const float r10 = sz * cy;
        const float r11 = cz * cx + sz * sy * sx;
        const float r12 = sz * sy * cx - cz * sx;
        const float r20 = -sy;
        const float r21 = cy * sx;
        const float r22 = cy * cx;

        float f;
        const int m = mapper[k];
        if (k == 0)        f = 1.0f;
        else if (k == 1)   f = cbl[b];
        else if (m < 0)    f = 1.0f;
        else               f = 2.0f / (1.0f + expf(-blc[b * NCORE + m] * 0.2f));

        float ox, oy, oz;
        if (k == 0) {
            ox = tpose[0]; oy = tpose[1]; oz = tpose[2];
        } else {
            ox = (tpose[k * 3 + 0] - tpose[p * 3 + 0]) * f;
            oy = (tpose[k * 3 + 1] - tpose[p * 3 + 1]) * f;
            oz = (tpose[k * 3 + 2] - tpose[p * 3 + 2]) * f;
        }
        Asm[w][k][0] = r00; Asm[w][k][1] = r01; Asm[w][k][2]  = r02; Asm[w][k][3]  = ox;
        Asm[w][k][4] = r10; Asm[w][k][5] = r11; Asm[w][k][6]  = r12; Asm[w][k][7]  = oy;
        Asm[w][k][8] = r20; Asm[w][k][9] = r21; Asm[w][k][10] = r22; Asm[w][k][11] = oz;
    }
    __syncthreads();

    if (k == 0) {
        #pragma unroll
        for (int j = 0; j < 12; ++j) Gsm[w][0][j] = Asm[w][0][j];
    }
    __syncthreads();

    const int depth = (k < NJ) ? (31 - __clz((unsigned)(k + 1))) : 99;
    for (int d = 1; d <= 5; ++d) {
        if (depth == d) {
            float gp[12], a[12], g[12];
            #pragma unroll
            for (int j = 0; j < 12; ++j) { gp[j] = Gsm[w][p][j]; a[j] = Asm[w][k][j]; }
            #pragma unroll
            for (int i = 0; i < 3; ++i) {
                #pragma unroll
                for (int j = 0; j < 4; ++j) {
                    float s = (j == 3) ? gp[i * 4 + 3] : 0.0f;
                    s = fmaf(gp[i * 4 + 0], a[0 * 4 + j], s);
                    s = fmaf(gp[i * 4 + 1], a[1 * 4 + j], s);
                    s = fmaf(gp[i * 4 + 2], a[2 * 4 + j], s);
                    g[i * 4 + j] = s;
                }
            }
            #pragma unroll
            for (int j = 0; j < 12; ++j) Gsm[w][k][j] = g[j];
        }
        __syncthreads();
    }

    if (k < NJ) {
        float g[12];
        #pragma unroll
        for (int j = 0; j < 12; ++j) g[j] = Gsm[w][k][j];
        const float jx = tpose[k * 3 + 0];
        const float jy = tpose[k * 3 + 1];
        const float jz = tpose[k * 3 + 2];
        const float s  = scale[b];
        Jout[(b * NJ + k) * 3 + 0] = fmaf(g[3],  s, trans[b * 3 + 0]);
        Jout[(b * NJ + k) * 3 + 1] = fmaf(g[7],  s, trans[b * 3 + 1]);
        Jout[(b * NJ + k) * 3 + 2] = fmaf(g[11], s, trans[b * 3 + 2]);
        float np[3];
        np[0] = g[3]  - (g[0] * jx + g[1] * jy + g[2]  * jz);
        np[1] = g[7]  - (g[4] * jx + g[5] * jy + g[6]  * jz);
        np[2] = g[11] - (g[8] * jx + g[9] * jy + g[10] * jz);
        #pragma unroll
        for (int i = 0; i < 3; ++i) {
            short4v o;
            o[0] = f2bf(g[i * 4 + 0]);
            o[1] = f2bf(g[i * 4 + 1]);
            o[2] = f2bf(g[i * 4 + 2]);
            o[3] = f2bf(np[i]);
            *(short4v*)&Bt[(size_t)(b * 3 + i) * KPAD + k * 4] = o;
        }
        if (k == 0) {
            short4v z = {0, 0, 0, 0};
            #pragma unroll
            for (int i = 0; i < 3; ++i) {
                *(short4v*)&Bt[(size_t)(b * 3 + i) * KPAD + 248] = z;
                *(short4v*)&Bt[(size_t)(b * 3 + i) * KPAD + 252] = z;
            }
        }
    }
}

// ---------------------------------------------------------------------------
// Kernel 2: wave-autonomous GEMM + epilogue.
// Grid 512 blocks x 256 thr. Wave (bid, wid): y = bid>>5 (16 batches,
// B-slab 48 rows held in 96 VGPRs, loaded once), stripe s = (bid&31)*4+wid;
// m-tiles s, s+128, ... Per tile: private 8KB A DMA (double-buffered,
// counted vmcnt, NO block barriers), 24 MFMA from regs, LDS transpose
// (wave-private region), coalesced float2 stores.
// bid%8 is y-invariant -> all 16 y-readers of a stripe share one XCD L2.
// ---------------------------------------------------------------------------
__global__ __launch_bounds__(256, 2) void gemm_skin(
    const short* __restrict__ WH,     // (MPAD, KPAD) bf16
    const short* __restrict__ Bt,     // (NN, KPAD) bf16
    const float* __restrict__ scale,  // (B,)
    const float* __restrict__ trans,  // (B*3,)
    float* __restrict__ out)          // (B, V, 3)
{
    __shared__ __align__(16) char lds_raw[65536 + 13312];  // A dbufs + epi

    const int tid  = threadIdx.x;
    const int wave = tid >> 6;
    const int lane = tid & 63;
    const int lrow = lane & 15;
    const int lk   = lane >> 4;
    const int y     = blockIdx.x >> 5;         // 0..15
    const int inner = blockIdx.x & 31;         // 0..31
    const int s     = inner * 4 + wave;        // stripe 0..127
    const int ntiles = (s < (MT - 7 * NSTRIPE)) ? 8 : 7;   // s<12 -> 8
    const int b0 = y * 16;

    char* Ab0 = lds_raw + wave * 16384;
    char* Ab1 = Ab0 + 8192;
    float* epi = (float*)(lds_raw + 65536) + wave * 800;   // 16 regions x 50 f

    // ---- stage B (24KB, overlays waves 0/1 A-dbufs transiently)
    {
        const char* Bsrc = (const char*)(Bt + (size_t)y * 48 * KPAD);
        #pragma unroll
        for (int cc = 0; cc < 6; ++cc) {
            const unsigned Lb = (unsigned)(wave * 6144 + cc * 1024);
            __builtin_amdgcn_global_load_lds(AS1(Bsrc + swz(Lb + lane * 16)),
                                             AS3(lds_raw + Lb), 16, 0, 0);
        }
    }
    WAITVM(0);
    __syncthreads();

    // ---- B slab -> registers (96 VGPR), swizzled reads
    short8v breg[3][8];
    #pragma unroll
    for (int nt = 0; nt < 3; ++nt) {
        const unsigned row = nt * 16 + lrow;
        const unsigned rb = row * 512, rx = (row & 7u) << 4;
        #pragma unroll
        for (int k8 = 0; k8 < 8; ++k8) {
            const unsigned cb = (unsigned)(k8 * 4 + lk) * 16;
            breg[nt][k8] = *(const short8v*)(lds_raw + rb + (cb ^ rx));
        }
    }
    __syncthreads();   // all waves done reading B before any A DMA overwrites

    // ---- per-thread invariants
    float sv[3], tv[3]; int bl3[3], ii3[3];
    #pragma unroll
    for (int nt = 0; nt < 3; ++nt) {
        const int n_loc = nt * 16 + lrow;
        bl3[nt] = n_loc / 3; ii3[nt] = n_loc - bl3[nt] * 3;
        sv[nt] = scale[b0 + bl3[nt]];
        tv[nt] = trans[(b0 + bl3[nt]) * 3 + ii3[nt]];
    }
    size_t sbase[6]; int loff[6], jj[6];
    #pragma unroll
    for (int it = 0; it < 6; ++it) {
        const int idx = it * 64 + lane;
        const int r = idx / 24, j = idx - r * 24;   // region, float2 index
        sbase[it] = (size_t)(b0 + r) * OUTF + 2 * j;
        loff[it]  = r * 50 + 2 * j;
        jj[it]    = j;
    }

    const unsigned arb = lrow * 512, arx = (lrow & 7u) << 4;
    const char* Asrc = (const char*)WH + (size_t)s * 8192;

    // ---- prologue: A[0]
    #pragma unroll
    for (int cc = 0; cc < 8; ++cc) {
        const unsigned Lb = cc * 1024;
        __builtin_amdgcn_global_load_lds(AS1(Asrc + swz(Lb + lane * 16)),
                                         AS3(Ab0 + Lb), 16, 0, 0);
    }
    WAITVM(0);

    for (int t = 0; t < ntiles; ++t) {
        char* bufR = (t & 1) ? Ab1 : Ab0;

        // issue next A tile (other buffer); its previous reads retired at t-1
        if (t + 1 < ntiles) {
            char* bufW = (t & 1) ? Ab0 : Ab1;
            const char* src = Asrc + (size_t)(t + 1) * (NSTRIPE * 8192);
            #pragma unroll
            for (int cc = 0; cc < 8; ++cc) {
                const unsigned Lb = cc * 1024;
                __builtin_amdgcn_global_load_lds(AS1(src + swz(Lb + lane * 16)),
                                                 AS3(bufW + Lb), 16, 0, 0);
            }
        }

        // A frags (swizzled) + MFMA against register B
        short8v af[8];
        #pragma unroll
        for (int k8 = 0; k8 < 8; ++k8) {
            const unsigned cb = (unsigned)(k8 * 4 + lk) * 16;
            af[k8] = *(const short8v*)(bufR + arb + (cb ^ arx));
        }
        floatx4 acc[3];
        #pragma unroll
        for (int nt = 0; nt < 3; ++nt) acc[nt] = (floatx4){0.f, 0.f, 0.f, 0.f};
        #pragma unroll
        for (int k8 = 0; k8 < 8; ++k8) {
            #pragma unroll
            for (int nt = 0; nt < 3; ++nt)
                acc[nt] = __builtin_amdgcn_mfma_f32_16x16x32_bf16(
                    af[k8], breg[nt][k8], acc[nt], 0, 0, 0);
        }

        // epilogue transpose (wave-private region; compiler orders DS ops)
        #pragma unroll
        for (int nt = 0; nt < 3; ++nt) {
            #pragma unroll
            for (int r = 0; r < 4; ++r)
                epi[bl3[nt] * 50 + (lk * 4 + r) * 3 + ii3[nt]] =
                    fmaf(acc[nt][r], sv[nt], tv[nt]);
        }

        // coalesced stores: 16 regions x 24 float2
        const int mtile = s + NSTRIPE * t;
        const int m48 = mtile * 48;
        const bool edge = (m48 + 48 > OUTF);
        #pragma unroll
        for (int it = 0; it < 6; ++it) {
            const floatx2 val = *(const floatx2*)&epi[loff[it]];
            if (!edge || m48 + 2 * jj[it] + 1 < OUTF)
                *(floatx2*)&out[sbase[it] + m48] = val;
        }

        // A[t+1] landed; the 6 stores stay in flight
        if (t + 1 < ntiles) WAITVM(6);
    }
}

extern "C" void kernel_launch(void* const* d_in, const int* in_sizes, int n_in,
                              void* d_out, int out_size, void* d_ws, size_t ws_size,
                              hipStream_t stream)
{
    const float* thetas  = (const float*)d_in[0];
    const float* blc     = (const float*)d_in[1];
    const float* cbl     = (const float*)d_in[2];
    const float* trans   = (const float*)d_in[3];
    const float* scale   = (const float*)d_in[4];
    const float* vtempl  = (const float*)d_in[5];
    const float* tpose   = (const float*)d_in[6];
    const float* weights = (const float*)d_in[7];
    const int*   parents = (const int*)d_in[8];
    const int*   mapper  = (const int*)d_in[9];

    float* out  = (float*)d_out;
    float* Jout = out + (size_t)NBATCH * NV * 3;

    short* WH = (short*)d_ws;                          // MPAD*KPAD bf16 = 7.44 MB
    short* Bt = WH + (size_t)MPAD * KPAD;              // NN*KPAD bf16 = 0.39 MB

    prep_kernel<<<64 + (MPAD * 32) / 256, 256, 0, stream>>>(
        thetas, blc, cbl, trans, scale, tpose, parents, mapper,
        weights, vtempl, Bt, WH, Jout);
    gemm_skin<<<512, 256, 0, stream>>>(WH, Bt, scale, trans, out);
}